// Round 1
// baseline (513.421 us; speedup 1.0000x reference)
//
#include <hip/hip_runtime.h>
#include <cstdint>
#include <cstddef>

// Problem constants (reference: M=8192, IN=4096, OUT=4096)
#define M_DIM 8192
#define K_DIM 4096
#define N_DIM 4096

typedef unsigned short u16;
typedef __bf16 bf16x8 __attribute__((ext_vector_type(8)));
typedef u16 u16x8 __attribute__((ext_vector_type(8)));
typedef float f32x4 __attribute__((ext_vector_type(4)));

// fp32 -> bf16 round-to-nearest-even (inputs are finite normals; no NaN path)
__device__ __forceinline__ u16 f2bf_rne(float f) {
  uint32_t u = __builtin_bit_cast(uint32_t, f);
  return (u16)((u + 0x7FFFu + ((u >> 16) & 1u)) >> 16);
}
// small int -> bf16 (exact for |i| <= 8)
__device__ __forceinline__ u16 i2bf(int i) {
  return (u16)(__builtin_bit_cast(uint32_t, (float)i) >> 16);
}

// ---------------- Pass 1a: x fp32 -> bf16 (8 elems/thread) ----------------
__global__ __launch_bounds__(256) void cvt_x_bf16(const float* __restrict__ x,
                                                  u16* __restrict__ xb) {
  size_t t = (size_t)blockIdx.x * 256 + threadIdx.x;
  const float4* xp = (const float4*)x;
  float4 a = xp[2 * t];
  float4 b = xp[2 * t + 1];
  u16x8 r;
  r[0] = f2bf_rne(a.x); r[1] = f2bf_rne(a.y); r[2] = f2bf_rne(a.z); r[3] = f2bf_rne(a.w);
  r[4] = f2bf_rne(b.x); r[5] = f2bf_rne(b.y); r[6] = f2bf_rne(b.z); r[7] = f2bf_rne(b.w);
  ((u16x8*)xb)[t] = r;
}

// ------- Pass 1b: packed int4 -> bf16 integer weights (scale deferred) -------
// wp[n][j] holds one byte: low nibble -> W[n][2j], high nibble -> W[n][2j+1],
// offset-binary -> two's complement via XOR 0x88 then 4-bit sign extension.
__global__ __launch_bounds__(256) void dequant_w4(const int* __restrict__ wp,
                                                  u16* __restrict__ wb) {
  size_t t = (size_t)blockIdx.x * 256 + threadIdx.x;
  int4 p = ((const int4*)wp)[t];
  u16x8 r;
  int v;
  v = p.x ^ 0x88; r[0] = i2bf((v << 28) >> 28); r[1] = i2bf((v << 24) >> 28);
  v = p.y ^ 0x88; r[2] = i2bf((v << 28) >> 28); r[3] = i2bf((v << 24) >> 28);
  v = p.z ^ 0x88; r[4] = i2bf((v << 28) >> 28); r[5] = i2bf((v << 24) >> 28);
  v = p.w ^ 0x88; r[6] = i2bf((v << 28) >> 28); r[7] = i2bf((v << 24) >> 28);
  ((u16x8*)wb)[t] = r;
}

// ---------------- Pass 2: bf16 gemm_bt (m97 structure) ----------------
// C[m][n] = (sum_k A[m][k]*B[n][k]) * scale[n] + bias[n]
// 128x128 tile, BK=64, 256 threads = 4 waves in 2x2 of 64x64,
// each wave 4x4 frags of mfma_f32_16x16x32_bf16, global_load_lds width 16.
__global__ __launch_bounds__(256, 2) void gemm_bt_w4a16(
    const u16* __restrict__ A,      // [M_DIM, K_DIM] bf16 bits
    const u16* __restrict__ B,      // [N_DIM, K_DIM] bf16 bits (integer weights)
    const float* __restrict__ scales,
    const float* __restrict__ bias,
    float* __restrict__ C) {
  __shared__ u16 sA[128 * 64];  // 16 KiB
  __shared__ u16 sB[128 * 64];  // 16 KiB

  const int tid = threadIdx.x;
  const int lane = tid & 63;
  const int wave = tid >> 6;
  const int m0 = blockIdx.y * 128;
  const int n0 = blockIdx.x * 128;
  const int wm = (wave & 1) * 64;
  const int wn = (wave >> 1) * 64;
  const int lrow = lane & 15;   // m (A/C) or n (B/C) within a 16x16 frag
  const int quad = lane >> 4;   // k-chunk selector for A/B, m-subrow for C/D

  f32x4 acc[4][4] = {};

  // Staging: thread tid covers LDS row tid/8 (+32 per round), k-chunk (tid%8)*8.
  // LDS flat bytes = tid*16 + round*4096  (matches global_load_lds lane*16 rule).
  const int srow = tid >> 3;
  const int schunk = (tid & 7) * 8;
  const u16* ga = A + (size_t)(m0 + srow) * K_DIM + schunk;
  const u16* gb = B + (size_t)(n0 + srow) * K_DIM + schunk;

  for (int kb = 0; kb < K_DIM; kb += 64) {
    __syncthreads();  // all waves done reading previous tile
#pragma unroll
    for (int r = 0; r < 4; ++r) {
      __builtin_amdgcn_global_load_lds(
          (const __attribute__((address_space(1))) void*)(ga + (size_t)(r * 32) * K_DIM + kb),
          (__attribute__((address_space(3))) void*)((char*)sA + wave * 1024 + r * 4096),
          16, 0, 0);
    }
#pragma unroll
    for (int r = 0; r < 4; ++r) {
      __builtin_amdgcn_global_load_lds(
          (const __attribute__((address_space(1))) void*)(gb + (size_t)(r * 32) * K_DIM + kb),
          (__attribute__((address_space(3))) void*)((char*)sB + wave * 1024 + r * 4096),
          16, 0, 0);
    }
    __syncthreads();  // compiler drains vmcnt(0) before s_barrier -> tile visible

#pragma unroll
    for (int s = 0; s < 2; ++s) {
      u16x8 af[4], bfr[4];
#pragma unroll
      for (int i = 0; i < 4; ++i)
        af[i] = *(const u16x8*)(sA + (wm + i * 16 + lrow) * 64 + s * 32 + quad * 8);
#pragma unroll
      for (int j = 0; j < 4; ++j)
        bfr[j] = *(const u16x8*)(sB + (wn + j * 16 + lrow) * 64 + s * 32 + quad * 8);
#pragma unroll
      for (int i = 0; i < 4; ++i)
#pragma unroll
        for (int j = 0; j < 4; ++j)
          acc[i][j] = __builtin_amdgcn_mfma_f32_16x16x32_bf16(
              __builtin_bit_cast(bf16x8, af[i]),
              __builtin_bit_cast(bf16x8, bfr[j]), acc[i][j], 0, 0, 0);
    }
  }

  // Epilogue: C/D layout col = lane&15 (n), row = quad*4 + reg (m). Apply
  // per-output-row scale + bias here (keeps MFMA inputs exact integers).
#pragma unroll
  for (int j = 0; j < 4; ++j) {
    const int n = n0 + wn + j * 16 + lrow;
    const float sc = scales[n];
    const float bi = bias[n];
#pragma unroll
    for (int i = 0; i < 4; ++i) {
#pragma unroll
      for (int r = 0; r < 4; ++r) {
        const int m = m0 + wm + i * 16 + quad * 4 + r;
        C[(size_t)m * N_DIM + n] = acc[i][j][r] * sc + bi;
      }
    }
  }
}

// ---------------- Fallback (ws too small): fp32 direct, correct but slow ----
__global__ __launch_bounds__(256) void fallback_w4a16(
    const float* __restrict__ x, const int* __restrict__ wp,
    const float* __restrict__ scales, const float* __restrict__ bias,
    float* __restrict__ out) {
  const int n = blockIdx.x * 256 + threadIdx.x;
  const int m = blockIdx.y;
  const float* xr = x + (size_t)m * K_DIM;
  const int* wr = wp + (size_t)n * (K_DIM / 2);
  float acc = 0.f;
  for (int j = 0; j < K_DIM / 2; ++j) {
    int w = wr[j] ^ 0x88;
    float lo = (float)((w << 28) >> 28);
    float hi = (float)((w << 24) >> 28);
    acc += xr[2 * j] * lo + xr[2 * j + 1] * hi;
  }
  out[(size_t)m * N_DIM + n] = acc * scales[n] + bias[n];
}

extern "C" void kernel_launch(void* const* d_in, const int* in_sizes, int n_in,
                              void* d_out, int out_size, void* d_ws, size_t ws_size,
                              hipStream_t stream) {
  const float* x = (const float*)d_in[0];
  const int* wp = (const int*)d_in[1];
  const float* sc = (const float*)d_in[2];
  const float* bi = (const float*)d_in[3];
  float* out = (float*)d_out;

  const size_t xb_elems = (size_t)M_DIM * K_DIM;           // 33.55M u16 = 64 MiB
  const size_t wb_elems = (size_t)N_DIM * K_DIM;           // 16.78M u16 = 32 MiB
  const size_t need = (xb_elems + wb_elems) * sizeof(u16); // 100,663,296 B

  if (ws_size >= need) {
    u16* xb = (u16*)d_ws;
    u16* wb = xb + xb_elems;
    cvt_x_bf16<<<(int)(xb_elems / 8 / 256), 256, 0, stream>>>(x, xb);
    dequant_w4<<<(int)((size_t)N_DIM * (K_DIM / 2) / 4 / 256), 256, 0, stream>>>(wp, wb);
    gemm_bt_w4a16<<<dim3(N_DIM / 128, M_DIM / 128), 256, 0, stream>>>(xb, wb, sc, bi, out);
  } else {
    fallback_w4a16<<<dim3(N_DIM / 256, M_DIM), 256, 0, stream>>>(x, wp, sc, bi, out);
  }
}

// Round 2
// 478.492 us; speedup vs baseline: 1.0730x; 1.0730x over previous
//
#include <hip/hip_runtime.h>
#include <cstdint>
#include <cstddef>

// Problem constants (reference: M=8192, IN=4096, OUT=4096)
#define M_DIM 8192
#define K_DIM 4096
#define N_DIM 4096

typedef unsigned short u16;
typedef __bf16 bf16x8 __attribute__((ext_vector_type(8)));
typedef u16 u16x8 __attribute__((ext_vector_type(8)));
typedef float f32x4 __attribute__((ext_vector_type(4)));

// fp32 -> bf16 round-to-nearest-even (inputs are finite normals; no NaN path)
__device__ __forceinline__ u16 f2bf_rne(float f) {
  uint32_t u = __builtin_bit_cast(uint32_t, f);
  return (u16)((u + 0x7FFFu + ((u >> 16) & 1u)) >> 16);
}
// small int -> bf16 (exact for |i| <= 8)
__device__ __forceinline__ u16 i2bf(int i) {
  return (u16)(__builtin_bit_cast(uint32_t, (float)i) >> 16);
}

#define XBLKS 16384  // M*K/8/256 blocks for the x-conversion half
#define WBLKS 8192   // N*(K/2)/4/256 blocks for the weight-dequant half

// ---- Fused prep: x fp32->bf16 and packed-int4 -> bf16 integer weights ----
// Block-uniform branch (no divergence). Scale stays deferred to GEMM epilogue
// so weight values in LDS/MFMA are exact small integers.
__global__ __launch_bounds__(256) void prep(const float* __restrict__ x,
                                            const int* __restrict__ wp,
                                            u16* __restrict__ xb,
                                            u16* __restrict__ wb) {
  const int b = blockIdx.x;
  if (b < XBLKS) {
    size_t t = (size_t)b * 256 + threadIdx.x;
    const float4* xp = (const float4*)x;
    float4 a = xp[2 * t];
    float4 c = xp[2 * t + 1];
    u16x8 r;
    r[0] = f2bf_rne(a.x); r[1] = f2bf_rne(a.y); r[2] = f2bf_rne(a.z); r[3] = f2bf_rne(a.w);
    r[4] = f2bf_rne(c.x); r[5] = f2bf_rne(c.y); r[6] = f2bf_rne(c.z); r[7] = f2bf_rne(c.w);
    ((u16x8*)xb)[t] = r;
  } else {
    size_t t = (size_t)(b - XBLKS) * 256 + threadIdx.x;
    int4 p = ((const int4*)wp)[t];
    u16x8 r;
    int v;
    v = p.x ^ 0x88; r[0] = i2bf((v << 28) >> 28); r[1] = i2bf((v << 24) >> 28);
    v = p.y ^ 0x88; r[2] = i2bf((v << 28) >> 28); r[3] = i2bf((v << 24) >> 28);
    v = p.z ^ 0x88; r[4] = i2bf((v << 28) >> 28); r[5] = i2bf((v << 24) >> 28);
    v = p.w ^ 0x88; r[6] = i2bf((v << 28) >> 28); r[7] = i2bf((v << 24) >> 28);
    ((u16x8*)wb)[t] = r;
  }
}

// ---------------- bf16 gemm_bt (m97 structure) + XOR bank swizzle ----------
// C[m][n] = (sum_k A[m][k]*B[n][k]) * scale[n] + bias[n]
// 128x128 tile, BK=64, 256 threads = 4 waves in 2x2 of 64x64,
// each wave 4x4 frags of mfma_f32_16x16x32_bf16, global_load_lds width 16.
//
// Swizzle: LDS tile row stride = 64 u16 = 128 B = exactly 32 banks, so the
// natural layout gives ~16-way conflicts on ds_read_b128 (all lanes of a quad
// hit one 4-bank group). Fix without padding (global_load_lds forbids pads):
// thread tid stages global 16B-chunk ((tid&7) ^ (row&7)) so LDS slot p of row
// r holds chunk p^(r&7); readers address slot c^(lrow&7). Banks then span all
// 32 with 2 lanes/bank (2-way = free per m136).
__global__ __launch_bounds__(256, 2) void gemm_bt_w4a16(
    const u16* __restrict__ A,      // [M_DIM, K_DIM] bf16 bits
    const u16* __restrict__ B,      // [N_DIM, K_DIM] bf16 bits (integer weights)
    const float* __restrict__ scales,
    const float* __restrict__ bias,
    float* __restrict__ C) {
  __shared__ u16 sA[128 * 64];  // 16 KiB
  __shared__ u16 sB[128 * 64];  // 16 KiB

  const int tid = threadIdx.x;
  const int lane = tid & 63;
  const int wave = tid >> 6;
  const int m0 = blockIdx.y * 128;
  const int n0 = blockIdx.x * 128;
  const int wm = (wave & 1) * 64;
  const int wn = (wave >> 1) * 64;
  const int lrow = lane & 15;   // m (A/C) or n (B/C) within a 16x16 frag
  const int quad = lane >> 4;   // k-chunk selector for A/B, m-subrow for C/D

  f32x4 acc[4][4] = {};

  // Staging: thread tid covers LDS row tid/8 (+32 per round). Global k-chunk
  // is XOR-swizzled by row parity; key (tid>>3)&7 is invariant across rounds
  // since rounds step rows by 32 (== 0 mod 8).
  const int srow = tid >> 3;
  const int key = srow & 7;
  const int schunk = ((tid & 7) ^ key) * 8;
  const u16* ga = A + (size_t)(m0 + srow) * K_DIM + schunk;
  const u16* gb = B + (size_t)(n0 + srow) * K_DIM + schunk;

  for (int kb = 0; kb < K_DIM; kb += 64) {
    __syncthreads();  // all waves done reading previous tile
#pragma unroll
    for (int r = 0; r < 4; ++r) {
      __builtin_amdgcn_global_load_lds(
          (const __attribute__((address_space(1))) void*)(ga + (size_t)(r * 32) * K_DIM + kb),
          (__attribute__((address_space(3))) void*)((char*)sA + wave * 1024 + r * 4096),
          16, 0, 0);
    }
#pragma unroll
    for (int r = 0; r < 4; ++r) {
      __builtin_amdgcn_global_load_lds(
          (const __attribute__((address_space(1))) void*)(gb + (size_t)(r * 32) * K_DIM + kb),
          (__attribute__((address_space(3))) void*)((char*)sB + wave * 1024 + r * 4096),
          16, 0, 0);
    }
    __syncthreads();  // vmcnt(0) drain before s_barrier -> tile visible

#pragma unroll
    for (int s = 0; s < 2; ++s) {
      u16x8 af[4], bfr[4];
#pragma unroll
      for (int i = 0; i < 4; ++i)
        af[i] = *(const u16x8*)(sA + (wm + i * 16 + lrow) * 64 +
                                ((s * 4 + quad) ^ (lrow & 7)) * 8);
#pragma unroll
      for (int j = 0; j < 4; ++j)
        bfr[j] = *(const u16x8*)(sB + (wn + j * 16 + lrow) * 64 +
                                 ((s * 4 + quad) ^ (lrow & 7)) * 8);
#pragma unroll
      for (int i = 0; i < 4; ++i)
#pragma unroll
        for (int j = 0; j < 4; ++j)
          acc[i][j] = __builtin_amdgcn_mfma_f32_16x16x32_bf16(
              __builtin_bit_cast(bf16x8, af[i]),
              __builtin_bit_cast(bf16x8, bfr[j]), acc[i][j], 0, 0, 0);
    }
  }

  // Epilogue: C/D layout col = lane&15 (n), row = quad*4 + reg (m). Apply
  // per-output-row scale + bias here (keeps MFMA inputs exact integers).
#pragma unroll
  for (int j = 0; j < 4; ++j) {
    const int n = n0 + wn + j * 16 + lrow;
    const float sc = scales[n];
    const float bi = bias[n];
#pragma unroll
    for (int i = 0; i < 4; ++i) {
#pragma unroll
      for (int r = 0; r < 4; ++r) {
        const int m = m0 + wm + i * 16 + quad * 4 + r;
        C[(size_t)m * N_DIM + n] = acc[i][j][r] * sc + bi;
      }
    }
  }
}

// ---------------- Fallback (ws too small): fp32 direct, correct but slow ----
__global__ __launch_bounds__(256) void fallback_w4a16(
    const float* __restrict__ x, const int* __restrict__ wp,
    const float* __restrict__ scales, const float* __restrict__ bias,
    float* __restrict__ out) {
  const int n = blockIdx.x * 256 + threadIdx.x;
  const int m = blockIdx.y;
  const float* xr = x + (size_t)m * K_DIM;
  const int* wr = wp + (size_t)n * (K_DIM / 2);
  float acc = 0.f;
  for (int j = 0; j < K_DIM / 2; ++j) {
    int w = wr[j] ^ 0x88;
    float lo = (float)((w << 28) >> 28);
    float hi = (float)((w << 24) >> 28);
    acc += xr[2 * j] * lo + xr[2 * j + 1] * hi;
  }
  out[(size_t)m * N_DIM + n] = acc * scales[n] + bias[n];
}

extern "C" void kernel_launch(void* const* d_in, const int* in_sizes, int n_in,
                              void* d_out, int out_size, void* d_ws, size_t ws_size,
                              hipStream_t stream) {
  const float* x = (const float*)d_in[0];
  const int* wp = (const int*)d_in[1];
  const float* sc = (const float*)d_in[2];
  const float* bi = (const float*)d_in[3];
  float* out = (float*)d_out;

  const size_t xb_elems = (size_t)M_DIM * K_DIM;           // 33.55M u16 = 64 MiB
  const size_t wb_elems = (size_t)N_DIM * K_DIM;           // 16.78M u16 = 32 MiB
  const size_t need = (xb_elems + wb_elems) * sizeof(u16); // 100,663,296 B

  if (ws_size >= need) {
    u16* xb = (u16*)d_ws;
    u16* wb = xb + xb_elems;
    prep<<<XBLKS + WBLKS, 256, 0, stream>>>(x, wp, xb, wb);
    gemm_bt_w4a16<<<dim3(N_DIM / 128, M_DIM / 128), 256, 0, stream>>>(xb, wb, sc, bi, out);
  } else {
    fallback_w4a16<<<dim3(N_DIM / 256, M_DIM), 256, 0, stream>>>(x, wp, sc, bi, out);
  }
}